// Round 2
// baseline (233.683 us; speedup 1.0000x reference)
//
#include <hip/hip_runtime.h>

// Gray-Scott PDE residual, t-looped formulation.
//   in  : (T=20, B=8, C=3, H=256, W=256) fp32; u = ch1, v = ch2
//   out : [f_u | f_v], each (20,8,1,252,252) fp32
//
// One thread owns a (b, y, x-pair) column and marches t=0..19, keeping the
// rolling time-stencil (c_{t-2}, c_{t-1}, c_t, lap_{t-1}) in registers so
// every input element is fetched from HBM exactly once (spatial stencil
// re-reads resolve in L1/L2 among concurrently-running neighbor threads).
// Output for timestep t-1 is emitted during iteration t (needs c_t).

#define IN_W   256
#define OUT_W  252
#define OUT_H  252
#define T_DIM  20
#define B_DIM  8

__global__ __launch_bounds__(256) void gs_loss_kernel(
    const float* __restrict__ in, float* __restrict__ out)
{
    int gid = blockIdx.x * blockDim.x + threadIdx.x;
    int xg  = gid & 127;           // 128 x-groups per row, 126 active
    if (xg >= 126) return;
    int r   = gid >> 7;            // row id: 0 .. 2015
    int b   = r & 7;               // b fastest -> blockIdx%8 ~ XCD keeps one/two b per XCD L2
    int y   = r >> 3;              // 0 .. 251
    int x0  = xg * 2;

    const int planeStride = IN_W * IN_W;        // 65536
    const int bStride     = 3 * planeStride;    // one (t,b) group = 3 channels
    const int tStride     = B_DIM * bStride;

    // u-plane (channel 1) stencil-center address at t=0
    const float* base = in + (size_t)b * bStride + planeStride
                           + (size_t)(y + 2) * IN_W + (x0 + 2);

    const int tOut = B_DIM * OUT_H * OUT_W;     // 508032 per timestep per tensor
    const int total = T_DIM * tOut;
    float* outu = out + ((size_t)b * OUT_H + y) * OUT_W + x0;
    float* outv = outu + total;

    const float c1      = 4.0f / 3.0f;
    const float c2      = 1.0f / 12.0f;
    const float inv_dx2 = 1.0f / (0.15625f * 0.15625f);   // DX = 20/128
    const float inv_dt  = 20.0f;                          // 1/DT, DT = 0.05
    const float Du = 0.16f, Dv = 0.08f, fR = 0.06f, kR = 0.062f;

    // rolling state (post-shift invariant: cc=c_t, cm1=c_{t-1}, cm2=c_{t-2}, lm1=l_t)
    float2 u_cm2 = {0,0}, u_cm1 = {0,0}, u_cc = {0,0}, u_lm1 = {0,0}, u_l0 = {0,0};
    float2 v_cm2 = {0,0}, v_cm1 = {0,0}, v_cc = {0,0}, v_lm1 = {0,0}, v_l0 = {0,0};

    for (int t = 0; t < T_DIM; ++t) {
        const float* up = base + (size_t)t * tStride;
        const float* vp = up + planeStride;

        float2 u_ym2 = *(const float2*)(up - 2 * IN_W);
        float2 u_ym1 = *(const float2*)(up - IN_W);
        float2 u_a   = *(const float2*)(up - 2);
        float2 u_c   = *(const float2*)(up);
        float2 u_e   = *(const float2*)(up + 2);
        float2 u_yp1 = *(const float2*)(up + IN_W);
        float2 u_yp2 = *(const float2*)(up + 2 * IN_W);

        float2 v_ym2 = *(const float2*)(vp - 2 * IN_W);
        float2 v_ym1 = *(const float2*)(vp - IN_W);
        float2 v_a   = *(const float2*)(vp - 2);
        float2 v_c   = *(const float2*)(vp);
        float2 v_e   = *(const float2*)(vp + 2);
        float2 v_yp1 = *(const float2*)(vp + IN_W);
        float2 v_yp2 = *(const float2*)(vp + 2 * IN_W);

        float2 lu, lv;
        lu.x = (c1 * (u_a.y + u_c.y + u_ym1.x + u_yp1.x)
              - c2 * (u_a.x + u_e.x + u_ym2.x + u_yp2.x)
              - 5.0f * u_c.x) * inv_dx2;
        lu.y = (c1 * (u_c.x + u_e.x + u_ym1.y + u_yp1.y)
              - c2 * (u_a.y + u_e.y + u_ym2.y + u_yp2.y)
              - 5.0f * u_c.y) * inv_dx2;
        lv.x = (c1 * (v_a.y + v_c.y + v_ym1.x + v_yp1.x)
              - c2 * (v_a.x + v_e.x + v_ym2.x + v_yp2.x)
              - 5.0f * v_c.x) * inv_dx2;
        lv.y = (c1 * (v_c.x + v_e.x + v_ym1.y + v_yp1.y)
              - c2 * (v_a.y + v_e.y + v_ym2.y + v_yp2.y)
              - 5.0f * v_c.y) * inv_dx2;

        float2 ucn = u_c;   // centers at t
        float2 vcn = v_c;

        if (t == 0) { u_l0 = lu; v_l0 = lv; }

        if (t == 2) {
            // emit t=0 (one-sided): c0=cm1, c1=cc, c2=new
            float2 ut, vt, fu, fv;
            ut.x = (-1.5f * u_cm1.x + 2.0f * u_cc.x - 0.5f * ucn.x) * inv_dt;
            ut.y = (-1.5f * u_cm1.y + 2.0f * u_cc.y - 0.5f * ucn.y) * inv_dt;
            vt.x = (-1.5f * v_cm1.x + 2.0f * v_cc.x - 0.5f * vcn.x) * inv_dt;
            vt.y = (-1.5f * v_cm1.y + 2.0f * v_cc.y - 0.5f * vcn.y) * inv_dt;
            float uvvx = u_cm1.x * v_cm1.x * v_cm1.x;
            float uvvy = u_cm1.y * v_cm1.y * v_cm1.y;
            fu.x = Du * u_l0.x - uvvx + fR * (1.0f - u_cm1.x) - ut.x;
            fu.y = Du * u_l0.y - uvvy + fR * (1.0f - u_cm1.y) - ut.y;
            fv.x = Dv * v_l0.x + uvvx - (fR + kR) * v_cm1.x - vt.x;
            fv.y = Dv * v_l0.y + uvvy - (fR + kR) * v_cm1.y - vt.y;
            *(float2*)(outu) = fu;
            *(float2*)(outv) = fv;
        }

        if (t >= 2) {
            // emit t-1 (interior): u_t = (c_t - c_{t-2}) / (2 DT)
            float2 ut, vt, fu, fv;
            ut.x = (ucn.x - u_cm1.x) * (0.5f * inv_dt);
            ut.y = (ucn.y - u_cm1.y) * (0.5f * inv_dt);
            vt.x = (vcn.x - v_cm1.x) * (0.5f * inv_dt);
            vt.y = (vcn.y - v_cm1.y) * (0.5f * inv_dt);
            float uvvx = u_cc.x * v_cc.x * v_cc.x;
            float uvvy = u_cc.y * v_cc.y * v_cc.y;
            fu.x = Du * u_lm1.x - uvvx + fR * (1.0f - u_cc.x) - ut.x;
            fu.y = Du * u_lm1.y - uvvy + fR * (1.0f - u_cc.y) - ut.y;
            fv.x = Dv * v_lm1.x + uvvx - (fR + kR) * v_cc.x - vt.x;
            fv.y = Dv * v_lm1.y + uvvy - (fR + kR) * v_cc.y - vt.y;
            *(float2*)(outu + (size_t)(t - 1) * tOut) = fu;
            *(float2*)(outv + (size_t)(t - 1) * tOut) = fv;
        }

        // shift
        u_cm2 = u_cm1; u_cm1 = u_cc; u_cc = ucn; u_lm1 = lu;
        v_cm2 = v_cm1; v_cm1 = v_cc; v_cc = vcn; v_lm1 = lv;
    }

    // emit t=19 (one-sided): c17=cm2, c18=cm1, c19=cc, lap19=lm1
    {
        float2 ut, vt, fu, fv;
        ut.x = (0.5f * u_cm2.x - 2.0f * u_cm1.x + 1.5f * u_cc.x) * inv_dt;
        ut.y = (0.5f * u_cm2.y - 2.0f * u_cm1.y + 1.5f * u_cc.y) * inv_dt;
        vt.x = (0.5f * v_cm2.x - 2.0f * v_cm1.x + 1.5f * v_cc.x) * inv_dt;
        vt.y = (0.5f * v_cm2.y - 2.0f * v_cm1.y + 1.5f * v_cc.y) * inv_dt;
        float uvvx = u_cc.x * v_cc.x * v_cc.x;
        float uvvy = u_cc.y * v_cc.y * v_cc.y;
        fu.x = Du * u_lm1.x - uvvx + fR * (1.0f - u_cc.x) - ut.x;
        fu.y = Du * u_lm1.y - uvvy + fR * (1.0f - u_cc.y) - ut.y;
        fv.x = Dv * v_lm1.x + uvvx - (fR + kR) * v_cc.x - vt.x;
        fv.y = Dv * v_lm1.y + uvvy - (fR + kR) * v_cc.y - vt.y;
        *(float2*)(outu + (size_t)(T_DIM - 1) * tOut) = fu;
        *(float2*)(outv + (size_t)(T_DIM - 1) * tOut) = fv;
    }
}

extern "C" void kernel_launch(void* const* d_in, const int* in_sizes, int n_in,
                              void* d_out, int out_size, void* d_ws, size_t ws_size,
                              hipStream_t stream) {
    const float* in = (const float*)d_in[0];
    float* out = (float*)d_out;

    // 2016 rows (8 b * 252 y) * 128 x-groups = 258048 threads
    const int threads = 256;
    const int blocks = (2016 * 128) / threads;   // 1008
    gs_loss_kernel<<<blocks, threads, 0, stream>>>(in, out);
}

// Round 3
// 201.828 us; speedup vs baseline: 1.1578x; 1.1578x over previous
//
#include <hip/hip_runtime.h>

// Gray-Scott PDE residual, t-marching, float4-per-thread, T split in halves.
//   in  : (T=20, B=8, C=3, H=256, W=256) fp32; u = ch1, v = ch2
//   out : [f_u | f_v], each (20,8,1,252,252) fp32
//
// Thread owns 4 consecutive x outputs of one (b,y) row and marches 11 t-planes
// (half 0 emits t=0..9, half 1 emits t=10..19; planes 9,10 read twice).
// Rolling registers hold c_{t-2}, c_{t-1}, c_t, lap_{t-1} so each input plane
// is fetched from HBM once per half. Block = 64 x-groups x 4 consecutive y of
// a single b, so y-halo stencil reads hit L1/XCD-L2.

#define T_OUT (8 * 252 * 252)

#define GS_INT(c) { \
    float ut = (ucn.c - u_cm1.c) * hdt; \
    float vt = (vcn.c - v_cm1.c) * hdt; \
    float uvv = u_cc.c * v_cc.c * v_cc.c; \
    fu.c = Du * u_lm1.c - uvv + fR * (1.0f - u_cc.c) - ut; \
    fv.c = Dv * v_lm1.c + uvv - (fR + kR) * v_cc.c - vt; }

#define GS_T0(c) { \
    float ut = (-1.5f * u_cm1.c + 2.0f * u_cc.c - 0.5f * ucn.c) * inv_dt; \
    float vt = (-1.5f * v_cm1.c + 2.0f * v_cc.c - 0.5f * vcn.c) * inv_dt; \
    float uvv = u_cm1.c * v_cm1.c * v_cm1.c; \
    fu.c = Du * u_l0.c - uvv + fR * (1.0f - u_cm1.c) - ut; \
    fv.c = Dv * v_l0.c + uvv - (fR + kR) * v_cm1.c - vt; }

#define GS_TN(c) { \
    float ut = (0.5f * u_cm2.c - 2.0f * u_cm1.c + 1.5f * u_cc.c) * inv_dt; \
    float vt = (0.5f * v_cm2.c - 2.0f * v_cm1.c + 1.5f * v_cc.c) * inv_dt; \
    float uvv = u_cc.c * v_cc.c * v_cc.c; \
    fu.c = Du * u_lm1.c - uvv + fR * (1.0f - u_cc.c) - ut; \
    fv.c = Dv * v_lm1.c + uvv - (fR + kR) * v_cc.c - vt; }

__global__ __launch_bounds__(256) void gs_loss_kernel(
    const float* __restrict__ in, float* __restrict__ out)
{
    const int tid  = threadIdx.x;
    const int xg   = tid & 63;          // x-group within row (63 active)
    const int yloc = tid >> 6;          // 0..3
    if (xg >= 63) return;

    const int bidx  = blockIdx.x;
    const int b     = bidx & 7;         // XCD-locality: one b per XCD slot
    const int rest  = bidx >> 3;
    const int ytile = rest % 63;
    const int h     = rest / 63;        // T-half: 0 emits t=0..9, 1 emits 10..19

    const int y  = ytile * 4 + yloc;    // 0..251
    const int x0 = xg * 4;              // 0..248, 16B-aligned in the plane row

    const int planeStride = 256 * 256;
    const int bStride     = 3 * planeStride;
    const int tStride     = 8 * bStride;

    // u-plane (ch1) address of row y+2, col x0 (window start; centers at +2..+5)
    const float* ubase = in + (size_t)b * bStride + planeStride
                         + (size_t)(y + 2) * 256 + x0;

    const int total = 20 * T_OUT;
    float* outu = out + ((size_t)b * 252 + y) * 252 + x0;
    float* outv = outu + total;

    const float C1 = 4.0f / 3.0f, C2 = 1.0f / 12.0f;
    const float inv_dx2 = 1.0f / (0.15625f * 0.15625f);   // DX = 20/128
    const float inv_dt  = 20.0f;                          // 1/DT
    const float hdt     = 10.0f;                          // 1/(2 DT)
    const float Du = 0.16f, Dv = 0.08f, fR = 0.06f, kR = 0.062f;

    float4 u_cm2{}, u_cm1{}, u_cc{}, u_lm1{}, u_l0{};
    float4 v_cm2{}, v_cm1{}, v_cc{}, v_lm1{}, v_l0{};

    const int t_begin = h ? 9 : 0;

    for (int i = 0; i <= 10; ++i) {
        const int t = t_begin + i;
        const float* up = ubase + (size_t)t * tStride;
        const float* vp = up + planeStride;

        // center row: 8 floats as two aligned float4 (c0..c7 = cols x0..x0+7)
        float4 uL = *(const float4*)(up);
        float4 uR = *(const float4*)(up + 4);
        // halo rows: middle 4 floats (cols x0+2..x0+5) as two aligned float2
        float2 um1a = *(const float2*)(up - 256 + 2), um1b = *(const float2*)(up - 256 + 4);
        float2 up1a = *(const float2*)(up + 256 + 2), up1b = *(const float2*)(up + 256 + 4);
        float2 um2a = *(const float2*)(up - 512 + 2), um2b = *(const float2*)(up - 512 + 4);
        float2 up2a = *(const float2*)(up + 512 + 2), up2b = *(const float2*)(up + 512 + 4);

        float4 vL = *(const float4*)(vp);
        float4 vR = *(const float4*)(vp + 4);
        float2 vm1a = *(const float2*)(vp - 256 + 2), vm1b = *(const float2*)(vp - 256 + 4);
        float2 vp1a = *(const float2*)(vp + 256 + 2), vp1b = *(const float2*)(vp + 256 + 4);
        float2 vm2a = *(const float2*)(vp - 512 + 2), vm2b = *(const float2*)(vp - 512 + 4);
        float2 vp2a = *(const float2*)(vp + 512 + 2), vp2b = *(const float2*)(vp + 512 + 4);

        float4 lu, lv;
        lu.x = (C1*(uL.y + uL.w + um1a.x + up1a.x) - C2*(uL.x + uR.x + um2a.x + up2a.x) - 5.0f*uL.z) * inv_dx2;
        lu.y = (C1*(uL.z + uR.x + um1a.y + up1a.y) - C2*(uL.y + uR.y + um2a.y + up2a.y) - 5.0f*uL.w) * inv_dx2;
        lu.z = (C1*(uL.w + uR.y + um1b.x + up1b.x) - C2*(uL.z + uR.z + um2b.x + up2b.x) - 5.0f*uR.x) * inv_dx2;
        lu.w = (C1*(uR.x + uR.z + um1b.y + up1b.y) - C2*(uL.w + uR.w + um2b.y + up2b.y) - 5.0f*uR.y) * inv_dx2;
        lv.x = (C1*(vL.y + vL.w + vm1a.x + vp1a.x) - C2*(vL.x + vR.x + vm2a.x + vp2a.x) - 5.0f*vL.z) * inv_dx2;
        lv.y = (C1*(vL.z + vR.x + vm1a.y + vp1a.y) - C2*(vL.y + vR.y + vm2a.y + vp2a.y) - 5.0f*vL.w) * inv_dx2;
        lv.z = (C1*(vL.w + vR.y + vm1b.x + vp1b.x) - C2*(vL.z + vR.z + vm2b.x + vp2b.x) - 5.0f*vR.x) * inv_dx2;
        lv.w = (C1*(vR.x + vR.z + vm1b.y + vp1b.y) - C2*(vL.w + vR.w + vm2b.y + vp2b.y) - 5.0f*vR.y) * inv_dx2;

        float4 ucn = make_float4(uL.z, uL.w, uR.x, uR.y);   // centers at t
        float4 vcn = make_float4(vL.z, vL.w, vR.x, vR.y);

        if (h == 0 && i == 0) { u_l0 = lu; v_l0 = lv; }

        if (h == 0 && i == 2) {
            // emit t=0 one-sided: c0=cm1, c1=cc, c2=ucn
            float4 fu, fv;
            GS_T0(x); GS_T0(y); GS_T0(z); GS_T0(w);
            *(float4*)(outu) = fu;
            *(float4*)(outv) = fv;
        }

        if (i >= 2) {
            // emit t-1 interior: center=cc (c_{t-1}), u_t=(c_t - c_{t-2})/(2DT), lap=lm1
            float4 fu, fv;
            GS_INT(x); GS_INT(y); GS_INT(z); GS_INT(w);
            *(float4*)(outu + (size_t)(t - 1) * T_OUT) = fu;
            *(float4*)(outv + (size_t)(t - 1) * T_OUT) = fv;
        }

        u_cm2 = u_cm1; u_cm1 = u_cc; u_cc = ucn; u_lm1 = lu;
        v_cm2 = v_cm1; v_cm1 = v_cc; v_cc = vcn; v_lm1 = lv;
    }

    if (h == 1) {
        // emit t=19 one-sided: c17=cm2, c18=cm1, c19=cc, lap19=lm1
        float4 fu, fv;
        GS_TN(x); GS_TN(y); GS_TN(z); GS_TN(w);
        *(float4*)(outu + (size_t)19 * T_OUT) = fu;
        *(float4*)(outv + (size_t)19 * T_OUT) = fv;
    }
}

extern "C" void kernel_launch(void* const* d_in, const int* in_sizes, int n_in,
                              void* d_out, int out_size, void* d_ws, size_t ws_size,
                              hipStream_t stream) {
    const float* in = (const float*)d_in[0];
    float* out = (float*)d_out;

    // 8 b * 63 y-tiles * 2 T-halves = 1008 blocks of 256 threads
    const int blocks = 8 * 63 * 2;
    gs_loss_kernel<<<blocks, 256, 0, stream>>>(in, out);
}

// Round 4
// 196.925 us; speedup vs baseline: 1.1867x; 1.0249x over previous
//
#include <hip/hip_runtime.h>

// Gray-Scott PDE residual, full t-march (no T-split), float4/thread,
// nontemporal output stores, XCD-pinned batches.
//   in  : (T=20, B=8, C=3, H=256, W=256) fp32; u = ch1, v = ch2
//   out : [f_u | f_v], each (20,8,1,252,252) fp32
//
// Grid = 504 blocks (8 b * 63 y-tiles) of 256 threads = 1.97 blocks/CU, all
// resident. b = blockIdx%8 pins each batch to one XCD so y-halo re-reads
// between adjacent y-tiles hit that XCD's L2. Each thread owns 4 x-outputs of
// one (b,y) row and marches t=0..19 with rolling registers (c_{t-2}, c_{t-1},
// c_t, lap_{t-1}); every input plane is fetched exactly once. Output stores
// are nontemporal so 79 MB of streaming writes don't evict the input halo
// working set from L2.

#define T_OUT (8 * 252 * 252)

typedef float vf4 __attribute__((ext_vector_type(4)));

static __device__ __forceinline__ vf4 ldu4(const float* p) {
    vf4 v;
    __builtin_memcpy(&v, p, 16);   // 8B-aligned 16B load; gfx950 handles it
    return v;
}

#define GS_INT(c) { \
    float ut = (ucn.c - u_cm1.c) * hdt; \
    float vt = (vcn.c - v_cm1.c) * hdt; \
    float uvv = u_cc.c * v_cc.c * v_cc.c; \
    fu.c = Du * u_lm1.c - uvv + fR * (1.0f - u_cc.c) - ut; \
    fv.c = Dv * v_lm1.c + uvv - (fR + kR) * v_cc.c - vt; }

#define GS_T0(c) { \
    float ut = (-1.5f * u_cm1.c + 2.0f * u_cc.c - 0.5f * ucn.c) * inv_dt; \
    float vt = (-1.5f * v_cm1.c + 2.0f * v_cc.c - 0.5f * vcn.c) * inv_dt; \
    float uvv = u_cm1.c * v_cm1.c * v_cm1.c; \
    fu.c = Du * u_l0.c - uvv + fR * (1.0f - u_cm1.c) - ut; \
    fv.c = Dv * v_l0.c + uvv - (fR + kR) * v_cm1.c - vt; }

#define GS_TN(c) { \
    float ut = (0.5f * u_cm2.c - 2.0f * u_cm1.c + 1.5f * u_cc.c) * inv_dt; \
    float vt = (0.5f * v_cm2.c - 2.0f * v_cm1.c + 1.5f * v_cc.c) * inv_dt; \
    float uvv = u_cc.c * v_cc.c * v_cc.c; \
    fu.c = Du * u_lm1.c - uvv + fR * (1.0f - u_cc.c) - ut; \
    fv.c = Dv * v_lm1.c + uvv - (fR + kR) * v_cc.c - vt; }

__global__ __launch_bounds__(256) void gs_loss_kernel(
    const float* __restrict__ in, float* __restrict__ out)
{
    const int tid  = threadIdx.x;
    const int xg   = tid & 63;          // 63 active x-groups of 4
    const int yloc = tid >> 6;          // 0..3
    if (xg >= 63) return;

    const int b     = blockIdx.x & 7;   // batch -> XCD pinning
    const int ytile = blockIdx.x >> 3;  // 0..62

    const int y  = ytile * 4 + yloc;    // 0..251
    const int x0 = xg * 4;              // 16B-aligned plane column

    const int planeStride = 256 * 256;
    const int bStride     = 3 * planeStride;
    const int tStride     = 8 * bStride;

    // u-plane (ch1) address of row y+2, col x0 (centers at cols x0+2..x0+5)
    const float* ubase = in + (size_t)b * bStride + planeStride
                         + (size_t)(y + 2) * 256 + x0;

    const int total = 20 * T_OUT;
    float* outu = out + ((size_t)b * 252 + y) * 252 + x0;
    float* outv = outu + total;

    const float C1 = 4.0f / 3.0f, C2 = 1.0f / 12.0f;
    const float inv_dx2 = 1.0f / (0.15625f * 0.15625f);   // DX = 20/128
    const float inv_dt  = 20.0f;                          // 1/DT
    const float hdt     = 10.0f;                          // 1/(2 DT)
    const float Du = 0.16f, Dv = 0.08f, fR = 0.06f, kR = 0.062f;

    vf4 u_cm2{}, u_cm1{}, u_cc{}, u_lm1{}, u_l0{};
    vf4 v_cm2{}, v_cm1{}, v_cc{}, v_lm1{}, v_l0{};

    for (int t = 0; t < 20; ++t) {
        const float* up = ubase + (size_t)t * tStride;
        const float* vp = up + planeStride;

        // center row: cols x0..x0+7 as two aligned 16B loads
        vf4 uL = *(const vf4*)(up);
        vf4 uR = *(const vf4*)(up + 4);
        // halo rows: cols x0+2..x0+5 as one (8B-aligned) 16B load each
        vf4 um1 = ldu4(up - 256 + 2);
        vf4 up1 = ldu4(up + 256 + 2);
        vf4 um2 = ldu4(up - 512 + 2);
        vf4 up2 = ldu4(up + 512 + 2);

        vf4 vL = *(const vf4*)(vp);
        vf4 vR = *(const vf4*)(vp + 4);
        vf4 vm1 = ldu4(vp - 256 + 2);
        vf4 vp1 = ldu4(vp + 256 + 2);
        vf4 vm2 = ldu4(vp - 512 + 2);
        vf4 vp2 = ldu4(vp + 512 + 2);

        vf4 lu, lv;
        lu.x = (C1*(uL.y + uL.w + um1.x + up1.x) - C2*(uL.x + uR.x + um2.x + up2.x) - 5.0f*uL.z) * inv_dx2;
        lu.y = (C1*(uL.z + uR.x + um1.y + up1.y) - C2*(uL.y + uR.y + um2.y + up2.y) - 5.0f*uL.w) * inv_dx2;
        lu.z = (C1*(uL.w + uR.y + um1.z + up1.z) - C2*(uL.z + uR.z + um2.z + up2.z) - 5.0f*uR.x) * inv_dx2;
        lu.w = (C1*(uR.x + uR.z + um1.w + up1.w) - C2*(uL.w + uR.w + um2.w + up2.w) - 5.0f*uR.y) * inv_dx2;
        lv.x = (C1*(vL.y + vL.w + vm1.x + vp1.x) - C2*(vL.x + vR.x + vm2.x + vp2.x) - 5.0f*vL.z) * inv_dx2;
        lv.y = (C1*(vL.z + vR.x + vm1.y + vp1.y) - C2*(vL.y + vR.y + vm2.y + vp2.y) - 5.0f*vL.w) * inv_dx2;
        lv.z = (C1*(vL.w + vR.y + vm1.z + vp1.z) - C2*(vL.z + vR.z + vm2.z + vp2.z) - 5.0f*vR.x) * inv_dx2;
        lv.w = (C1*(vR.x + vR.z + vm1.w + vp1.w) - C2*(vL.w + vR.w + vm2.w + vp2.w) - 5.0f*vR.y) * inv_dx2;

        vf4 ucn = {uL.z, uL.w, uR.x, uR.y};   // centers at t
        vf4 vcn = {vL.z, vL.w, vR.x, vR.y};

        if (t == 0) { u_l0 = lu; v_l0 = lv; }

        if (t == 2) {
            // emit t=0 one-sided: c0=cm1, c1=cc, c2=ucn, lap=l0
            vf4 fu, fv;
            GS_T0(x); GS_T0(y); GS_T0(z); GS_T0(w);
            __builtin_nontemporal_store(fu, (vf4*)(outu));
            __builtin_nontemporal_store(fv, (vf4*)(outv));
        }

        if (t >= 2) {
            // emit t-1 interior: center=cc, u_t=(c_t - c_{t-2})/(2DT), lap=lm1
            vf4 fu, fv;
            GS_INT(x); GS_INT(y); GS_INT(z); GS_INT(w);
            __builtin_nontemporal_store(fu, (vf4*)(outu + (size_t)(t - 1) * T_OUT));
            __builtin_nontemporal_store(fv, (vf4*)(outv + (size_t)(t - 1) * T_OUT));
        }

        u_cm2 = u_cm1; u_cm1 = u_cc; u_cc = ucn; u_lm1 = lu;
        v_cm2 = v_cm1; v_cm1 = v_cc; v_cc = vcn; v_lm1 = lv;
    }

    // emit t=19 one-sided: c17=cm2, c18=cm1, c19=cc, lap19=lm1
    {
        vf4 fu, fv;
        GS_TN(x); GS_TN(y); GS_TN(z); GS_TN(w);
        __builtin_nontemporal_store(fu, (vf4*)(outu + (size_t)19 * T_OUT));
        __builtin_nontemporal_store(fv, (vf4*)(outv + (size_t)19 * T_OUT));
    }
}

extern "C" void kernel_launch(void* const* d_in, const int* in_sizes, int n_in,
                              void* d_out, int out_size, void* d_ws, size_t ws_size,
                              hipStream_t stream) {
    const float* in = (const float*)d_in[0];
    float* out = (float*)d_out;

    // 8 b * 63 y-tiles = 504 blocks of 256 threads (~2 blocks/CU, all resident)
    gs_loss_kernel<<<8 * 63, 256, 0, stream>>>(in, out);
}